// Round 8
// baseline (684.651 us; speedup 1.0000x reference)
//
#include <hip/hip_runtime.h>
#include <stdint.h>
#include <stddef.h>

#define NE 600000
#define NN 50000
#define CI 128
#define CH 256
#define EPSI 1e-5f

typedef __attribute__((ext_vector_type(8))) short bf8;
typedef __attribute__((ext_vector_type(4))) float f4;
typedef __attribute__((ext_vector_type(4))) unsigned int u4;

union FragU { bf8 h; uint32_t w[4]; };

__device__ __forceinline__ unsigned short f2bf(float f) {
  union { float f; uint32_t u; } v; v.f = f;
  uint32_t u = v.u;
  u += 0x7FFFu + ((u >> 16) & 1u);   // RNE
  return (unsigned short)(u >> 16);
}

__device__ __forceinline__ uint32_t cvtpk(float lo, float hi) {
  uint32_t r;
  asm("v_cvt_pk_bf16_f32 %0, %1, %2" : "=v"(r) : "v"(lo), "v"(hi));
  return r;
}

__device__ __forceinline__ float asf(uint32_t x) {
  union { uint32_t u; float f; } v; v.u = x; return v.f;
}

// Weight pack (verified rounds 3-7):
//  P1 (layer1, per net, 64KB): tau-permuted so D-regs of chunk c land as
//    lane kg's hids {32c+8kg+0..7}.
//  P2 (layer2, per net, 64KB): u16 P2[mt][c][l][j] = W2[32c+(l>>4)*8+j][16mt+(l&15)]
// ws u16 layout: [0)P1a [32768)P1b [65536)P2a [98304)P2b [131072) Ua bf16 [NN][256]
__global__ void pack_weights(const float* __restrict__ W1a, const float* __restrict__ W1b,
                             const float* __restrict__ W2a, const float* __restrict__ W2b,
                             unsigned short* __restrict__ ws) {
  int i = blockIdx.x * 256 + threadIdx.x;
  if (i >= 4 * 32768) return;
  int m = i >> 15;
  int r = i & 32767;
  int j = r & 7;
  int l = (r >> 3) & 63;
  int kg = l >> 4, q = l & 15;
  float val;
  if (m < 2) {
    int t = (r >> 9) & 3;
    int tau = (r >> 11) & 1;
    int c = (r >> 12) & 7;
    int cin = 32 * t + kg * 8 + j;
    int hid = 32 * c + 8 * (q >> 2) + 4 * tau + (q & 3);
    const float* W1 = (m == 0) ? W1a : W1b;
    val = W1[cin * CH + hid];
  } else {
    int c = (r >> 9) & 7;
    int mt = (r >> 12) & 7;
    int hid = 32 * c + kg * 8 + j;
    int cout = 16 * mt + q;
    const float* W2 = (m == 2) ? W2a : W2b;
    val = W2[hid * CI + cout];
  }
  ws[(size_t)m * 32768 + r] = f2bf(val);
}

// Ua[n][hid] = bf16( node[n] @ W1a + 0.5*b1a )  (no relu; summed per edge later)
__global__ __launch_bounds__(256)
void node_pre(const float* __restrict__ node, const float* __restrict__ b1a,
              const unsigned short* __restrict__ wp, unsigned short* __restrict__ Ua) {
  const int tid = threadIdx.x;
  const int lane = tid & 63;
  const int wv = tid >> 6;
  const int kg = lane >> 4, ar = lane & 15;
  const int n0 = blockIdx.x * 64 + wv * 16 + ar;
  const bool okn = (n0 < NN);
  const int n = okn ? n0 : (NN - 1);
  const float* pn = node + (size_t)n * CI;

  FragU xn[4];
#pragma unroll
  for (int t = 0; t < 4; ++t) {
    const int c0 = t * 32 + kg * 8;
    f4 v0 = *(const f4*)(pn + c0);
    f4 v1 = *(const f4*)(pn + c0 + 4);
    xn[t].w[0] = cvtpk(v0[0], v0[1]); xn[t].w[1] = cvtpk(v0[2], v0[3]);
    xn[t].w[2] = cvtpk(v1[0], v1[1]); xn[t].w[3] = cvtpk(v1[2], v1[3]);
  }
  const int lofs = lane * 8;
#pragma unroll 1
  for (int c = 0; c < 8; ++c) {
    f4 t0 = *(const f4*)(b1a + c * 32 + kg * 8) * 0.5f;
    f4 t1 = *(const f4*)(b1a + c * 32 + kg * 8 + 4) * 0.5f;
    const unsigned short* p1 = wp + c * 4096;
#pragma unroll
    for (int t = 0; t < 4; ++t) {
      bf8 a0 = *(const bf8*)(p1 + t * 512 + lofs);
      bf8 a1 = *(const bf8*)(p1 + 2048 + t * 512 + lofs);
      t0 = __builtin_amdgcn_mfma_f32_16x16x32_bf16(a0, xn[t].h, t0, 0, 0, 0);
      t1 = __builtin_amdgcn_mfma_f32_16x16x32_bf16(a1, xn[t].h, t1, 0, 0, 0);
    }
    u4 q;
    q[0] = cvtpk(t0[0], t0[1]); q[1] = cvtpk(t0[2], t0[3]);
    q[2] = cvtpk(t1[0], t1[1]); q[3] = cvtpk(t1[2], t1[3]);
    if (okn) *(u4*)(Ua + (size_t)n * CH + c * 32 + kg * 8) = q;
  }
}

// Fused edge kernel: 1024 threads = 16 waves, 32 edges/wave (2 sequential
// groups of 16). LDS 128 KB = P1b + P2b. Per group, the 8 dense net-b chunks
// (LDS) are software-pipelined with the 8 gather-dependent layer-2a chunks
// (issue u=c+2, consume u=c) so HBM gather latency hides under MFMA work.
__global__ __launch_bounds__(1024, 4)
void edge_fused(const unsigned short* __restrict__ Ua,
                const float* __restrict__ ef,
                const int* __restrict__ eidx,
                const float* __restrict__ b1b,
                const float* __restrict__ b2a, const float* __restrict__ b2b,
                const unsigned short* __restrict__ wp,
                float* __restrict__ out) {
  __shared__ __align__(16) unsigned short lw[65536];
  const int tid = threadIdx.x;
  const int lane = tid & 63;
  const int wv = tid >> 6;
  const int kg = lane >> 4, ar = lane & 15;
  const int lofs = lane * 8;

  // ---- stage P1b+P2b into LDS (consume after __syncthreads below)
  {
    const u4* s1 = (const u4*)(wp + 32768);
    const u4* s2 = (const u4*)(wp + 98304);
    u4* l = (u4*)lw;
#pragma unroll
    for (int i = 0; i < 4; ++i) {
      int o = i * 1024 + tid;
      l[o] = s1[o];
      l[4096 + o] = s2[o];
    }
  }

  const int be = blockIdx.x * 512 + wv * 32;
  const int e0 = be + ar, e1 = be + 16 + ar;
  const int ec0 = (e0 < NE) ? e0 : (NE - 1);
  const int ec1 = (e1 < NE) ? e1 : (NE - 1);
  const unsigned short* pUs0 = Ua + (size_t)eidx[ec0] * CH;
  const unsigned short* pUd0 = Ua + (size_t)eidx[NE + ec0] * CH;
  const unsigned short* pUs1 = Ua + (size_t)eidx[ec1] * CH;
  const unsigned short* pUd1 = Ua + (size_t)eidx[NE + ec1] * CH;

  FragU xe[4];       // shared between groups (sequential)
  f4 hacc[8];        // shared between groups (sequential)
  u4 avb[2], dvb[2]; // 2-deep pending gather buffers

  auto ldxe = [&](const float* pe) {
#pragma unroll
    for (int t = 0; t < 4; ++t) {
      const int c0 = t * 32 + kg * 8;
      f4 v0 = *(const f4*)(pe + c0);
      f4 v1 = *(const f4*)(pe + c0 + 4);
      xe[t].w[0] = cvtpk(v0[0], v0[1]); xe[t].w[1] = cvtpk(v0[2], v0[3]);
      xe[t].w[2] = cvtpk(v1[0], v1[1]); xe[t].w[3] = cvtpk(v1[2], v1[3]);
    }
  };

  auto hinit = [&]() {
#pragma unroll
    for (int mt = 0; mt < 8; ++mt) {
      f4 u = *(const f4*)(b2a + mt * 16 + kg * 4);
      f4 v = *(const f4*)(b2b + mt * 16 + kg * 4);
      hacc[mt] = u + v;
    }
  };

  // one edge-group: 8 pipelined iterations {issue u=c+2 | dense chunk c | consume u=c}
  auto rungrp = [&](const unsigned short* pUs, const unsigned short* pUd,
                    const unsigned short* pUsN, const unsigned short* pUdN) {
    const unsigned short* P2a = wp + 65536;
#pragma unroll
    for (int c = 0; c < 8; ++c) {
      // issue gathers 2 chunks ahead (rolls into next group's u=0,1 at c=6,7)
      u4 avN = {}, dvN = {};
      if (c < 6) {
        avN = *(const u4*)(pUs + (c + 2) * 32 + kg * 8);
        dvN = *(const u4*)(pUd + (c + 2) * 32 + kg * 8);
      } else if (pUsN) {
        avN = *(const u4*)(pUsN + (c - 6) * 32 + kg * 8);
        dvN = *(const u4*)(pUdN + (c - 6) * 32 + kg * 8);
      }
      // dense net-b chunk c (all operands LDS-resident)
      f4 t0 = *(const f4*)(b1b + c * 32 + kg * 8);
      f4 t1 = *(const f4*)(b1b + c * 32 + kg * 8 + 4);
#pragma unroll
      for (int t = 0; t < 4; ++t) {
        bf8 a0 = *(const bf8*)(lw + c * 4096 + t * 512 + lofs);
        bf8 a1 = *(const bf8*)(lw + c * 4096 + 2048 + t * 512 + lofs);
        t0 = __builtin_amdgcn_mfma_f32_16x16x32_bf16(a0, xe[t].h, t0, 0, 0, 0);
        t1 = __builtin_amdgcn_mfma_f32_16x16x32_bf16(a1, xe[t].h, t1, 0, 0, 0);
      }
      FragU bf_;
      bf_.w[0] = cvtpk(fmaxf(t0[0], 0.f), fmaxf(t0[1], 0.f));
      bf_.w[1] = cvtpk(fmaxf(t0[2], 0.f), fmaxf(t0[3], 0.f));
      bf_.w[2] = cvtpk(fmaxf(t1[0], 0.f), fmaxf(t1[1], 0.f));
      bf_.w[3] = cvtpk(fmaxf(t1[2], 0.f), fmaxf(t1[3], 0.f));
#pragma unroll
      for (int mt = 0; mt < 8; ++mt) {
        bf8 a2 = *(const bf8*)(lw + 32768 + (mt * 8 + c) * 512 + lofs);
        hacc[mt] = __builtin_amdgcn_mfma_f32_16x16x32_bf16(a2, bf_.h, hacc[mt], 0, 0, 0);
      }
      // consume gather u=c (issued 2 iterations ago): layer-2a chunk
      {
        u4 av = avb[c & 1], dv = dvb[c & 1];
        FragU tb;
#pragma unroll
        for (int i = 0; i < 4; ++i) {
          float lo = asf(av[i] << 16) + asf(dv[i] << 16);
          float hi = asf(av[i] & 0xFFFF0000u) + asf(dv[i] & 0xFFFF0000u);
          tb.w[i] = cvtpk(fmaxf(lo, 0.f), fmaxf(hi, 0.f));
        }
#pragma unroll
        for (int mt = 0; mt < 8; ++mt) {
          bf8 aW = *(const bf8*)(P2a + (mt * 8 + c) * 512 + lofs);
          hacc[mt] = __builtin_amdgcn_mfma_f32_16x16x32_bf16(aW, tb.h, hacc[mt], 0, 0, 0);
        }
      }
      avb[c & 1] = avN; dvb[c & 1] = dvN;
    }
  };

  auto phaseC = [&](int e) {
    float sum = 0.f, sq = 0.f;
#pragma unroll
    for (int mt = 0; mt < 8; ++mt)
#pragma unroll
      for (int i = 0; i < 4; ++i) { float v = hacc[mt][i]; sum += v; sq += v * v; }
    sum += __shfl_xor(sum, 16); sum += __shfl_xor(sum, 32);
    sq  += __shfl_xor(sq, 16);  sq  += __shfl_xor(sq, 32);
    const float mu = sum * (1.0f / 128.0f);
    const float var = sq * (1.0f / 128.0f) - mu * mu;
    const float rs = rsqrtf(var + EPSI);
    if (e < NE) {
      float* po = out + (size_t)e * CI;
      const float* pr = ef + (size_t)e * CI;
#pragma unroll
      for (int mt = 0; mt < 8; ++mt) {
        f4 r = *(const f4*)(pr + mt * 16 + kg * 4);
        f4 o;
#pragma unroll
        for (int i = 0; i < 4; ++i) {
          float n = (hacc[mt][i] - mu) * rs;
          o[i] = r[i] + fmaxf(n, 0.f);
        }
        *(f4*)(po + mt * 16 + kg * 4) = o;
      }
    }
  };

  // ---- group 0 prologue: ef frags, bias acc, gathers u=0,1 in flight
  ldxe(ef + (size_t)ec0 * CI);
  hinit();
  avb[0] = *(const u4*)(pUs0 + kg * 8);
  dvb[0] = *(const u4*)(pUd0 + kg * 8);
  avb[1] = *(const u4*)(pUs0 + 32 + kg * 8);
  dvb[1] = *(const u4*)(pUd0 + 32 + kg * 8);
  __syncthreads();   // LDS weights ready

  rungrp(pUs0, pUd0, pUs1, pUd1);   // leaves g1's u=0,1 in avb/dvb
  ldxe(ef + (size_t)ec1 * CI);      // issue g1 ef loads under phase C
  phaseC(e0);
  hinit();
  rungrp(pUs1, pUd1, nullptr, nullptr);
  phaseC(e1);
}

extern "C" void kernel_launch(void* const* d_in, const int* in_sizes, int n_in,
                              void* d_out, int out_size, void* d_ws, size_t ws_size,
                              hipStream_t stream) {
  const float* node = (const float*)d_in[0];
  const float* ef   = (const float*)d_in[1];
  const int* eidx   = (const int*)d_in[2];
  const float* W1a = (const float*)d_in[3];
  const float* b1a = (const float*)d_in[4];
  const float* W2a = (const float*)d_in[5];
  const float* b2a = (const float*)d_in[6];
  const float* W1b = (const float*)d_in[7];
  const float* b1b = (const float*)d_in[8];
  const float* W2b = (const float*)d_in[9];
  const float* b2b = (const float*)d_in[10];
  unsigned short* wp = (unsigned short*)d_ws;            // 256 KB packed weights
  unsigned short* Ua = wp + 131072;                       // 25.6 MB bf16 Ua
  float* outp = (float*)d_out;

  pack_weights<<<512, 256, 0, stream>>>(W1a, W1b, W2a, W2b, wp);
  node_pre<<<(NN + 63) / 64, 256, 0, stream>>>(node, b1a, wp, Ua);
  edge_fused<<<(NE + 511) / 512, 1024, 0, stream>>>(
      Ua, ef, eidx, b1b, b2a, b2b, wp, outp);
}

// Round 9
// 389.218 us; speedup vs baseline: 1.7590x; 1.7590x over previous
//
#include <hip/hip_runtime.h>
#include <stdint.h>
#include <stddef.h>

#define NE 600000
#define NN 50000
#define CI 128
#define CH 256
#define EPSI 1e-5f

typedef __attribute__((ext_vector_type(8))) short bf8;
typedef __attribute__((ext_vector_type(4))) float f4;
typedef __attribute__((ext_vector_type(4))) unsigned int u4;

union FragU { bf8 h; uint32_t w[4]; };

__device__ __forceinline__ unsigned short f2bf(float f) {
  union { float f; uint32_t u; } v; v.f = f;
  uint32_t u = v.u;
  u += 0x7FFFu + ((u >> 16) & 1u);   // RNE
  return (unsigned short)(u >> 16);
}

__device__ __forceinline__ uint32_t cvtpk(float lo, float hi) {
  uint32_t r;
  asm("v_cvt_pk_bf16_f32 %0, %1, %2" : "=v"(r) : "v"(lo), "v"(hi));
  return r;
}

__device__ __forceinline__ float asf(uint32_t x) {
  union { uint32_t u; float f; } v; v.u = x; return v.f;
}

// Weight pack (verified rounds 3-8):
//  P1 (layer1, per net, 64KB): tau-permuted so D-regs of chunk c land as
//    lane kg's hids {32c+8kg+0..7}.
//  P2 (layer2, per net, 64KB): u16 P2[mt][c][l][j] = W2[32c+(l>>4)*8+j][16mt+(l&15)]
// ws u16 layout: [0)P1a [32768)P1b [65536)P2a [98304)P2b [131072) Ua bf16 [NN][256]
__global__ void pack_weights(const float* __restrict__ W1a, const float* __restrict__ W1b,
                             const float* __restrict__ W2a, const float* __restrict__ W2b,
                             unsigned short* __restrict__ ws) {
  int i = blockIdx.x * 256 + threadIdx.x;
  if (i >= 4 * 32768) return;
  int m = i >> 15;
  int r = i & 32767;
  int j = r & 7;
  int l = (r >> 3) & 63;
  int kg = l >> 4, q = l & 15;
  float val;
  if (m < 2) {
    int t = (r >> 9) & 3;
    int tau = (r >> 11) & 1;
    int c = (r >> 12) & 7;
    int cin = 32 * t + kg * 8 + j;
    int hid = 32 * c + 8 * (q >> 2) + 4 * tau + (q & 3);
    const float* W1 = (m == 0) ? W1a : W1b;
    val = W1[cin * CH + hid];
  } else {
    int c = (r >> 9) & 7;
    int mt = (r >> 12) & 7;
    int hid = 32 * c + kg * 8 + j;
    int cout = 16 * mt + q;
    const float* W2 = (m == 2) ? W2a : W2b;
    val = W2[hid * CI + cout];
  }
  ws[(size_t)m * 32768 + r] = f2bf(val);
}

// Ua[n][hid] = bf16( node[n] @ W1a + 0.5*b1a )  (no relu; summed per edge later)
__global__ __launch_bounds__(256)
void node_pre(const float* __restrict__ node, const float* __restrict__ b1a,
              const unsigned short* __restrict__ wp, unsigned short* __restrict__ Ua) {
  const int tid = threadIdx.x;
  const int lane = tid & 63;
  const int wv = tid >> 6;
  const int kg = lane >> 4, ar = lane & 15;
  const int n0 = blockIdx.x * 64 + wv * 16 + ar;
  const bool okn = (n0 < NN);
  const int n = okn ? n0 : (NN - 1);
  const float* pn = node + (size_t)n * CI;

  FragU xn[4];
#pragma unroll
  for (int t = 0; t < 4; ++t) {
    const int c0 = t * 32 + kg * 8;
    f4 v0 = *(const f4*)(pn + c0);
    f4 v1 = *(const f4*)(pn + c0 + 4);
    xn[t].w[0] = cvtpk(v0[0], v0[1]); xn[t].w[1] = cvtpk(v0[2], v0[3]);
    xn[t].w[2] = cvtpk(v1[0], v1[1]); xn[t].w[3] = cvtpk(v1[2], v1[3]);
  }
  const int lofs = lane * 8;
#pragma unroll 1
  for (int c = 0; c < 8; ++c) {
    f4 t0 = *(const f4*)(b1a + c * 32 + kg * 8) * 0.5f;
    f4 t1 = *(const f4*)(b1a + c * 32 + kg * 8 + 4) * 0.5f;
    const unsigned short* p1 = wp + c * 4096;
#pragma unroll
    for (int t = 0; t < 4; ++t) {
      bf8 a0 = *(const bf8*)(p1 + t * 512 + lofs);
      bf8 a1 = *(const bf8*)(p1 + 2048 + t * 512 + lofs);
      t0 = __builtin_amdgcn_mfma_f32_16x16x32_bf16(a0, xn[t].h, t0, 0, 0, 0);
      t1 = __builtin_amdgcn_mfma_f32_16x16x32_bf16(a1, xn[t].h, t1, 0, 0, 0);
    }
    u4 q;
    q[0] = cvtpk(t0[0], t0[1]); q[1] = cvtpk(t0[2], t0[3]);
    q[2] = cvtpk(t1[0], t1[1]); q[3] = cvtpk(t1[2], t1[3]);
    if (okn) *(u4*)(Ua + (size_t)n * CH + c * 32 + kg * 8) = q;
  }
}

// 4-deep gather prefetch for phase B: issue chunk u's 4 loads, consume 4 later.
#define LD4(S0, D0, S1, D1, u) \
  S0 = *(const u4*)(pUs0 + (u) * 32 + kg * 8); \
  D0 = *(const u4*)(pUd0 + (u) * 32 + kg * 8); \
  S1 = *(const u4*)(pUs1 + (u) * 32 + kg * 8); \
  D1 = *(const u4*)(pUd1 + (u) * 32 + kg * 8);

#define CONSUME(S0, D0, S1, D1, u) { \
  FragU tb0, tb1; \
  _Pragma("unroll") \
  for (int i = 0; i < 4; ++i) { \
    float lo0 = asf(S0[i] << 16) + asf(D0[i] << 16); \
    float hi0 = asf(S0[i] & 0xFFFF0000u) + asf(D0[i] & 0xFFFF0000u); \
    tb0.w[i] = cvtpk(fmaxf(lo0, 0.f), fmaxf(hi0, 0.f)); \
    float lo1 = asf(S1[i] << 16) + asf(D1[i] << 16); \
    float hi1 = asf(S1[i] & 0xFFFF0000u) + asf(D1[i] & 0xFFFF0000u); \
    tb1.w[i] = cvtpk(fmaxf(lo1, 0.f), fmaxf(hi1, 0.f)); \
  } \
  _Pragma("unroll") \
  for (int mt = 0; mt < 8; ++mt) { \
    bf8 aW = *(const bf8*)(P2a + (mt * 8 + (u)) * 512 + lofs); \
    hacc[0][mt] = __builtin_amdgcn_mfma_f32_16x16x32_bf16(aW, tb0.h, hacc[0][mt], 0, 0, 0); \
    hacc[1][mt] = __builtin_amdgcn_mfma_f32_16x16x32_bf16(aW, tb1.h, hacc[1][mt], 0, 0, 0); \
  } }

// Fused edge kernel: 1024 threads = 16 waves, 32 edges/wave (2 groups of 16).
// LDS: [0,32768) u16 = P1b copy, [32768,65536) u16 = P2b copy (128 KB).
// Phase B gathers are 4-deep software-pipelined in named registers.
__global__ __launch_bounds__(1024, 4)
void edge_fused(const unsigned short* __restrict__ Ua,
                const float* __restrict__ ef,
                const int* __restrict__ eidx,
                const float* __restrict__ b1b,
                const float* __restrict__ b2a, const float* __restrict__ b2b,
                const unsigned short* __restrict__ wp,
                float* __restrict__ out) {
  __shared__ __align__(16) unsigned short lw[65536];
  const int tid = threadIdx.x;
  const int lane = tid & 63;
  const int wv = tid >> 6;
  const int kg = lane >> 4, ar = lane & 15;
  const int lofs = lane * 8;

  // ---- edge ids + index loads first (longest dependency chain)
  const int be = blockIdx.x * 512 + wv * 32;
  const int e0 = be + ar, e1 = be + 16 + ar;
  const int ec0 = (e0 < NE) ? e0 : (NE - 1);
  const int ec1 = (e1 < NE) ? e1 : (NE - 1);
  const int is0 = eidx[ec0], id0 = eidx[NE + ec0];
  const int is1 = eidx[ec1], id1 = eidx[NE + ec1];

  // ---- stage W1b+W2b into LDS (overlaps the eidx round-trip)
  {
    const u4* s1 = (const u4*)(wp + 32768);
    const u4* s2 = (const u4*)(wp + 98304);
    u4* l = (u4*)lw;
#pragma unroll
    for (int i = 0; i < 4; ++i) {
      int o = i * 1024 + tid;
      l[o] = s1[o];
      l[4096 + o] = s2[o];
    }
  }

  const unsigned short* pUs0 = Ua + (size_t)is0 * CH;
  const unsigned short* pUd0 = Ua + (size_t)id0 * CH;
  const unsigned short* pUs1 = Ua + (size_t)is1 * CH;
  const unsigned short* pUd1 = Ua + (size_t)id1 * CH;
  const unsigned short* P2a = wp + 65536;

  // ---- prologue: 4 chunks of gathers in flight (16 load instrs, 16 KB/wave)
  u4 As0, Ad0, As1, Ad1, Bs0, Bd0, Bs1, Bd1;
  u4 Cs0, Cd0, Cs1, Cd1, Ds0, Dd0, Ds1, Dd1;
  LD4(As0, Ad0, As1, Ad1, 0)
  LD4(Bs0, Bd0, Bs1, Bd1, 1)
  LD4(Cs0, Cd0, Cs1, Cd1, 2)
  LD4(Ds0, Dd0, Ds1, Dd1, 3)

  // ---- h^T accumulators (lane: edge ar, couts 16mt+4kg+i), b2a+b2b folded in
  f4 hacc[2][8];
#pragma unroll
  for (int mt = 0; mt < 8; ++mt) {
    f4 u = *(const f4*)(b2a + mt * 16 + kg * 4);
    f4 v = *(const f4*)(b2b + mt * 16 + kg * 4);
    hacc[0][mt] = u + v;
    hacc[1][mt] = u + v;
  }

  // ---- phase B: layer-2a, 4-deep pipelined
  CONSUME(As0, Ad0, As1, Ad1, 0) LD4(As0, Ad0, As1, Ad1, 4)
  CONSUME(Bs0, Bd0, Bs1, Bd1, 1) LD4(Bs0, Bd0, Bs1, Bd1, 5)
  CONSUME(Cs0, Cd0, Cs1, Cd1, 2) LD4(Cs0, Cd0, Cs1, Cd1, 6)
  CONSUME(Ds0, Dd0, Ds1, Dd1, 3) LD4(Ds0, Dd0, Ds1, Dd1, 7)
  CONSUME(As0, Ad0, As1, Ad1, 4)
  CONSUME(Bs0, Bd0, Bs1, Bd1, 5)
  CONSUME(Cs0, Cd0, Cs1, Cd1, 6)
  CONSUME(Ds0, Dd0, Ds1, Dd1, 7)

  __syncthreads();   // LDS weights ready

  // ---- phase A: net-b from LDS weights, group-sequential
#pragma unroll
  for (int g = 0; g < 2; ++g) {
    const int ecg = g ? ec1 : ec0;
    const float* pe = ef + (size_t)ecg * CI;
    FragU xe[4];
#pragma unroll
    for (int t = 0; t < 4; ++t) {
      const int c0 = t * 32 + kg * 8;
      f4 v0 = *(const f4*)(pe + c0);
      f4 v1 = *(const f4*)(pe + c0 + 4);
      xe[t].w[0] = cvtpk(v0[0], v0[1]); xe[t].w[1] = cvtpk(v0[2], v0[3]);
      xe[t].w[2] = cvtpk(v1[0], v1[1]); xe[t].w[3] = cvtpk(v1[2], v1[3]);
    }
#pragma unroll 1
    for (int c = 0; c < 8; ++c) {
      f4 t0 = *(const f4*)(b1b + c * 32 + kg * 8);
      f4 t1 = *(const f4*)(b1b + c * 32 + kg * 8 + 4);
#pragma unroll
      for (int t = 0; t < 4; ++t) {
        bf8 a0 = *(const bf8*)(lw + c * 4096 + t * 512 + lofs);
        bf8 a1 = *(const bf8*)(lw + c * 4096 + 2048 + t * 512 + lofs);
        t0 = __builtin_amdgcn_mfma_f32_16x16x32_bf16(a0, xe[t].h, t0, 0, 0, 0);
        t1 = __builtin_amdgcn_mfma_f32_16x16x32_bf16(a1, xe[t].h, t1, 0, 0, 0);
      }
      FragU bf_;
      bf_.w[0] = cvtpk(fmaxf(t0[0], 0.f), fmaxf(t0[1], 0.f));
      bf_.w[1] = cvtpk(fmaxf(t0[2], 0.f), fmaxf(t0[3], 0.f));
      bf_.w[2] = cvtpk(fmaxf(t1[0], 0.f), fmaxf(t1[1], 0.f));
      bf_.w[3] = cvtpk(fmaxf(t1[2], 0.f), fmaxf(t1[3], 0.f));
#pragma unroll
      for (int mt = 0; mt < 8; ++mt) {
        bf8 a2 = *(const bf8*)(lw + 32768 + (mt * 8 + c) * 512 + lofs);
        hacc[g][mt] = __builtin_amdgcn_mfma_f32_16x16x32_bf16(a2, bf_.h, hacc[g][mt], 0, 0, 0);
      }
    }
  }

  // ---- phase C: InstanceNorm + relu + residual + store, per group
#pragma unroll
  for (int g = 0; g < 2; ++g) {
    float sum = 0.f, sq = 0.f;
#pragma unroll
    for (int mt = 0; mt < 8; ++mt)
#pragma unroll
      for (int i = 0; i < 4; ++i) { float v = hacc[g][mt][i]; sum += v; sq += v * v; }
    sum += __shfl_xor(sum, 16); sum += __shfl_xor(sum, 32);
    sq  += __shfl_xor(sq, 16);  sq  += __shfl_xor(sq, 32);
    const float mu = sum * (1.0f / 128.0f);
    const float var = sq * (1.0f / 128.0f) - mu * mu;
    const float rs = rsqrtf(var + EPSI);
    const int e = g ? e1 : e0;
    if (e < NE) {
      float* po = out + (size_t)e * CI;
      const float* pr = ef + (size_t)e * CI;
#pragma unroll
      for (int mt = 0; mt < 8; ++mt) {
        f4 r = *(const f4*)(pr + mt * 16 + kg * 4);
        f4 o;
#pragma unroll
        for (int i = 0; i < 4; ++i) {
          float n = (hacc[g][mt][i] - mu) * rs;
          o[i] = r[i] + fmaxf(n, 0.f);
        }
        *(f4*)(po + mt * 16 + kg * 4) = o;
      }
    }
  }
}

extern "C" void kernel_launch(void* const* d_in, const int* in_sizes, int n_in,
                              void* d_out, int out_size, void* d_ws, size_t ws_size,
                              hipStream_t stream) {
  const float* node = (const float*)d_in[0];
  const float* ef   = (const float*)d_in[1];
  const int* eidx   = (const int*)d_in[2];
  const float* W1a = (const float*)d_in[3];
  const float* b1a = (const float*)d_in[4];
  const float* W2a = (const float*)d_in[5];
  const float* b2a = (const float*)d_in[6];
  const float* W1b = (const float*)d_in[7];
  const float* b1b = (const float*)d_in[8];
  const float* W2b = (const float*)d_in[9];
  const float* b2b = (const float*)d_in[10];
  unsigned short* wp = (unsigned short*)d_ws;            // 256 KB packed weights
  unsigned short* Ua = wp + 131072;                       // 25.6 MB bf16 Ua
  float* outp = (float*)d_out;

  pack_weights<<<512, 256, 0, stream>>>(W1a, W1b, W2a, W2b, wp);
  node_pre<<<(NN + 63) / 64, 256, 0, stream>>>(node, b1a, wp, Ua);
  edge_fused<<<(NE + 511) / 512, 1024, 0, stream>>>(
      Ua, ef, eidx, b1b, b2a, b2b, wp, outp);
}

// Round 10
// 369.593 us; speedup vs baseline: 1.8524x; 1.0531x over previous
//
#include <hip/hip_runtime.h>
#include <stdint.h>
#include <stddef.h>

#define NE 600000
#define NN 50000
#define CI 128
#define CH 256
#define EPSI 1e-5f

typedef __attribute__((ext_vector_type(8))) short bf8;
typedef __attribute__((ext_vector_type(4))) float f4;
typedef __attribute__((ext_vector_type(4))) unsigned int u4;

union FragU { bf8 h; uint32_t w[4]; };

__device__ __forceinline__ unsigned short f2bf(float f) {
  union { float f; uint32_t u; } v; v.f = f;
  uint32_t u = v.u;
  u += 0x7FFFu + ((u >> 16) & 1u);   // RNE
  return (unsigned short)(u >> 16);
}

__device__ __forceinline__ uint32_t cvtpk(float lo, float hi) {
  uint32_t r;
  asm("v_cvt_pk_bf16_f32 %0, %1, %2" : "=v"(r) : "v"(lo), "v"(hi));
  return r;
}

__device__ __forceinline__ float asf(uint32_t x) {
  union { uint32_t u; float f; } v; v.u = x; return v.f;
}

// Weight pack (verified rounds 3-9):
//  P1 (layer1, per net, 64KB): tau-permuted so D-regs of chunk c land as
//    lane kg's hids {32c+8kg+0..7}.
//  P2 (layer2, per net, 64KB): u16 P2[mt][c][l][j] = W2[32c+(l>>4)*8+j][16mt+(l&15)]
// ws u16 layout: [0)P1a [32768)P1b [65536)P2a [98304)P2b [131072) Ua bf16 [NN][256]
__global__ void pack_weights(const float* __restrict__ W1a, const float* __restrict__ W1b,
                             const float* __restrict__ W2a, const float* __restrict__ W2b,
                             unsigned short* __restrict__ ws) {
  int i = blockIdx.x * 256 + threadIdx.x;
  if (i >= 4 * 32768) return;
  int m = i >> 15;
  int r = i & 32767;
  int j = r & 7;
  int l = (r >> 3) & 63;
  int kg = l >> 4, q = l & 15;
  float val;
  if (m < 2) {
    int t = (r >> 9) & 3;
    int tau = (r >> 11) & 1;
    int c = (r >> 12) & 7;
    int cin = 32 * t + kg * 8 + j;
    int hid = 32 * c + 8 * (q >> 2) + 4 * tau + (q & 3);
    const float* W1 = (m == 0) ? W1a : W1b;
    val = W1[cin * CH + hid];
  } else {
    int c = (r >> 9) & 7;
    int mt = (r >> 12) & 7;
    int hid = 32 * c + kg * 8 + j;
    int cout = 16 * mt + q;
    const float* W2 = (m == 2) ? W2a : W2b;
    val = W2[hid * CI + cout];
  }
  ws[(size_t)m * 32768 + r] = f2bf(val);
}

// Ua[n][hid] = bf16( node[n] @ W1a + 0.5*b1a )  (no relu; summed per edge later)
__global__ __launch_bounds__(256)
void node_pre(const float* __restrict__ node, const float* __restrict__ b1a,
              const unsigned short* __restrict__ wp, unsigned short* __restrict__ Ua) {
  const int tid = threadIdx.x;
  const int lane = tid & 63;
  const int wv = tid >> 6;
  const int kg = lane >> 4, ar = lane & 15;
  const int n0 = blockIdx.x * 64 + wv * 16 + ar;
  const bool okn = (n0 < NN);
  const int n = okn ? n0 : (NN - 1);
  const float* pn = node + (size_t)n * CI;

  FragU xn[4];
#pragma unroll
  for (int t = 0; t < 4; ++t) {
    const int c0 = t * 32 + kg * 8;
    f4 v0 = *(const f4*)(pn + c0);
    f4 v1 = *(const f4*)(pn + c0 + 4);
    xn[t].w[0] = cvtpk(v0[0], v0[1]); xn[t].w[1] = cvtpk(v0[2], v0[3]);
    xn[t].w[2] = cvtpk(v1[0], v1[1]); xn[t].w[3] = cvtpk(v1[2], v1[3]);
  }
  const int lofs = lane * 8;
#pragma unroll 1
  for (int c = 0; c < 8; ++c) {
    f4 t0 = *(const f4*)(b1a + c * 32 + kg * 8) * 0.5f;
    f4 t1 = *(const f4*)(b1a + c * 32 + kg * 8 + 4) * 0.5f;
    const unsigned short* p1 = wp + c * 4096;
#pragma unroll
    for (int t = 0; t < 4; ++t) {
      bf8 a0 = *(const bf8*)(p1 + t * 512 + lofs);
      bf8 a1 = *(const bf8*)(p1 + 2048 + t * 512 + lofs);
      t0 = __builtin_amdgcn_mfma_f32_16x16x32_bf16(a0, xn[t].h, t0, 0, 0, 0);
      t1 = __builtin_amdgcn_mfma_f32_16x16x32_bf16(a1, xn[t].h, t1, 0, 0, 0);
    }
    u4 q;
    q[0] = cvtpk(t0[0], t0[1]); q[1] = cvtpk(t0[2], t0[3]);
    q[2] = cvtpk(t1[0], t1[1]); q[3] = cvtpk(t1[2], t1[3]);
    if (okn) *(u4*)(Ua + (size_t)n * CH + c * 32 + kg * 8) = q;
  }
}

// issue gather for hid-chunk u into named regs (8 VGPR per buffered chunk)
#define ISSUE(Sv, Dv, u) \
  Sv = *(const u4*)(pUs + (u) * 32 + kg * 8); \
  Dv = *(const u4*)(pUd + (u) * 32 + kg * 8);

// dense net-b chunk c: l1b (LDS P1b) -> relu -> l2b (LDS P2b), 16 MFMA
#define DENSE(c) { \
  f4 t0 = *(const f4*)(b1b + (c) * 32 + kg * 8); \
  f4 t1 = *(const f4*)(b1b + (c) * 32 + kg * 8 + 4); \
  _Pragma("unroll") \
  for (int t = 0; t < 4; ++t) { \
    bf8 a0 = *(const bf8*)(lw + (c) * 4096 + t * 512 + lofs); \
    bf8 a1 = *(const bf8*)(lw + (c) * 4096 + 2048 + t * 512 + lofs); \
    t0 = __builtin_amdgcn_mfma_f32_16x16x32_bf16(a0, xe[t].h, t0, 0, 0, 0); \
    t1 = __builtin_amdgcn_mfma_f32_16x16x32_bf16(a1, xe[t].h, t1, 0, 0, 0); \
  } \
  FragU bf_; \
  bf_.w[0] = cvtpk(fmaxf(t0[0], 0.f), fmaxf(t0[1], 0.f)); \
  bf_.w[1] = cvtpk(fmaxf(t0[2], 0.f), fmaxf(t0[3], 0.f)); \
  bf_.w[2] = cvtpk(fmaxf(t1[0], 0.f), fmaxf(t1[1], 0.f)); \
  bf_.w[3] = cvtpk(fmaxf(t1[2], 0.f), fmaxf(t1[3], 0.f)); \
  _Pragma("unroll") \
  for (int mt = 0; mt < 8; ++mt) { \
    bf8 a2 = *(const bf8*)(lw + 32768 + (mt * 8 + (c)) * 512 + lofs); \
    hacc[mt] = __builtin_amdgcn_mfma_f32_16x16x32_bf16(a2, bf_.h, hacc[mt], 0, 0, 0); \
  } }

// consume gathered chunk u: T1 = relu(Ua[s]+Ua[d]) -> l2a (W2a from L2), 8 MFMA
#define CONS(Sv, Dv, u) { \
  FragU tb; \
  _Pragma("unroll") \
  for (int i = 0; i < 4; ++i) { \
    float lo = asf(Sv[i] << 16) + asf(Dv[i] << 16); \
    float hi = asf(Sv[i] & 0xFFFF0000u) + asf(Dv[i] & 0xFFFF0000u); \
    tb.w[i] = cvtpk(fmaxf(lo, 0.f), fmaxf(hi, 0.f)); \
  } \
  _Pragma("unroll") \
  for (int mt = 0; mt < 8; ++mt) { \
    bf8 aW = *(const bf8*)(P2a + (mt * 8 + (u)) * 512 + lofs); \
    hacc[mt] = __builtin_amdgcn_mfma_f32_16x16x32_bf16(aW, tb.h, hacc[mt], 0, 0, 0); \
  } }

// Fused edge kernel: 1024 threads = 16 waves, 16 edges/wave (256/block).
// LDS 128 KB = P1b + P2b. Barrier at start only; waves then free-run through
// a merged per-chunk loop {DENSE | CONS | ISSUE+2} so gather latency hides
// under dense MFMA work and waves desync instead of phase-locking.
__global__ __launch_bounds__(1024, 4)
void edge_fused(const unsigned short* __restrict__ Ua,
                const float* __restrict__ ef,
                const int* __restrict__ eidx,
                const float* __restrict__ b1b,
                const float* __restrict__ b2a, const float* __restrict__ b2b,
                const unsigned short* __restrict__ wp,
                float* __restrict__ out) {
  __shared__ __align__(16) unsigned short lw[65536];
  const int tid = threadIdx.x;
  const int lane = tid & 63;
  const int wv = tid >> 6;
  const int kg = lane >> 4, ar = lane & 15;
  const int lofs = lane * 8;

  // ---- edge id + gather bases (longest dep chain first)
  const int e = blockIdx.x * 256 + wv * 16 + ar;
  const int ec = (e < NE) ? e : (NE - 1);
  const int is = eidx[ec], id = eidx[NE + ec];
  const unsigned short* pUs = Ua + (size_t)is * CH;
  const unsigned short* pUd = Ua + (size_t)id * CH;
  const unsigned short* P2a = wp + 65536;

  // ---- stage P1b+P2b into LDS
  {
    const u4* s1 = (const u4*)(wp + 32768);
    const u4* s2 = (const u4*)(wp + 98304);
    u4* l = (u4*)lw;
#pragma unroll
    for (int i = 0; i < 4; ++i) {
      int o = i * 1024 + tid;
      l[o] = s1[o];
      l[4096 + o] = s2[o];
    }
  }

  // ---- per-edge ef fragments (issued pre-barrier to overlap the drain)
  const float* pe = ef + (size_t)ec * CI;
  FragU xe[4];
#pragma unroll
  for (int t = 0; t < 4; ++t) {
    const int c0 = t * 32 + kg * 8;
    f4 v0 = *(const f4*)(pe + c0);
    f4 v1 = *(const f4*)(pe + c0 + 4);
    xe[t].w[0] = cvtpk(v0[0], v0[1]); xe[t].w[1] = cvtpk(v0[2], v0[3]);
    xe[t].w[2] = cvtpk(v1[0], v1[1]); xe[t].w[3] = cvtpk(v1[2], v1[3]);
  }

  // ---- h^T accumulator (lane: edge ar, couts 16mt+4kg+i), b2a+b2b folded in
  f4 hacc[8];
#pragma unroll
  for (int mt = 0; mt < 8; ++mt) {
    f4 u = *(const f4*)(b2a + mt * 16 + kg * 4);
    f4 v = *(const f4*)(b2b + mt * 16 + kg * 4);
    hacc[mt] = u + v;
  }

  __syncthreads();   // single sync: LDS weights ready; waves free-run after

  // ---- merged loop, 2-deep gather double-buffer in named regs
  u4 As, Ad, Bs, Bd;
  ISSUE(As, Ad, 0)
  ISSUE(Bs, Bd, 1)
  DENSE(0) CONS(As, Ad, 0) ISSUE(As, Ad, 2)
  DENSE(1) CONS(Bs, Bd, 1) ISSUE(Bs, Bd, 3)
  DENSE(2) CONS(As, Ad, 2) ISSUE(As, Ad, 4)
  DENSE(3) CONS(Bs, Bd, 3) ISSUE(Bs, Bd, 5)
  DENSE(4) CONS(As, Ad, 4) ISSUE(As, Ad, 6)
  DENSE(5) CONS(Bs, Bd, 5) ISSUE(Bs, Bd, 7)
  DENSE(6) CONS(As, Ad, 6)
  DENSE(7) CONS(Bs, Bd, 7)

  // ---- InstanceNorm + relu + residual + store
  {
    float sum = 0.f, sq = 0.f;
#pragma unroll
    for (int mt = 0; mt < 8; ++mt)
#pragma unroll
      for (int i = 0; i < 4; ++i) { float v = hacc[mt][i]; sum += v; sq += v * v; }
    sum += __shfl_xor(sum, 16); sum += __shfl_xor(sum, 32);
    sq  += __shfl_xor(sq, 16);  sq  += __shfl_xor(sq, 32);
    const float mu = sum * (1.0f / 128.0f);
    const float var = sq * (1.0f / 128.0f) - mu * mu;
    const float rs = rsqrtf(var + EPSI);
    if (e < NE) {
      float* po = out + (size_t)e * CI;
      const float* pr = ef + (size_t)e * CI;
#pragma unroll
      for (int mt = 0; mt < 8; ++mt) {
        f4 r = *(const f4*)(pr + mt * 16 + kg * 4);
        f4 o;
#pragma unroll
        for (int i = 0; i < 4; ++i) {
          float n = (hacc[mt][i] - mu) * rs;
          o[i] = r[i] + fmaxf(n, 0.f);
        }
        *(f4*)(po + mt * 16 + kg * 4) = o;
      }
    }
  }
}

extern "C" void kernel_launch(void* const* d_in, const int* in_sizes, int n_in,
                              void* d_out, int out_size, void* d_ws, size_t ws_size,
                              hipStream_t stream) {
  const float* node = (const float*)d_in[0];
  const float* ef   = (const float*)d_in[1];
  const int* eidx   = (const int*)d_in[2];
  const float* W1a = (const float*)d_in[3];
  const float* b1a = (const float*)d_in[4];
  const float* W2a = (const float*)d_in[5];
  const float* b2a = (const float*)d_in[6];
  const float* W1b = (const float*)d_in[7];
  const float* b1b = (const float*)d_in[8];
  const float* W2b = (const float*)d_in[9];
  const float* b2b = (const float*)d_in[10];
  unsigned short* wp = (unsigned short*)d_ws;            // 256 KB packed weights
  unsigned short* Ua = wp + 131072;                       // 25.6 MB bf16 Ua
  float* outp = (float*)d_out;

  pack_weights<<<512, 256, 0, stream>>>(W1a, W1b, W2a, W2b, wp);
  node_pre<<<(NN + 63) / 64, 256, 0, stream>>>(node, b1a, wp, Ua);
  edge_fused<<<(NE + 255) / 256, 1024, 0, stream>>>(
      Ua, ef, eidx, b1b, b2a, b2b, wp, outp);
}